// Round 2
// baseline (3078.292 us; speedup 1.0000x reference)
//
#include <hip/hip_runtime.h>

enum { TT = 2048, HH = 64, BB = 64, GG = 256, VV = 256 };

// LDS-only barrier: does NOT drain vmcnt (global loads/stores stay in flight).
// Safe when the barrier only protects LDS traffic (CK's block_sync_lds pattern).
static __device__ __forceinline__ void bar_lds(){
  asm volatile("s_waitcnt lgkmcnt(0)\n\ts_barrier" ::: "memory");
}

// ---------------- K1: embW[v][g] = emb[v]·w_ih[g] + b_ih[g] + b_hh[g] ----------------
__global__ __launch_bounds__(256) void k_embw(const float* __restrict__ emb,
                                              const float* __restrict__ w_ih,
                                              const float* __restrict__ b_ih,
                                              const float* __restrict__ b_hh,
                                              float* __restrict__ embW){
  int v = blockIdx.x, g = threadIdx.x;
  __shared__ float e[HH];
  if (g < HH) e[g] = emb[v*HH + g];
  bar_lds();
  float acc = b_ih[g] + b_hh[g];
  const float* wr = w_ih + g*HH;
#pragma unroll
  for (int k = 0; k < HH; k += 4){
    float4 w4 = *(const float4*)(wr + k);
    acc = fmaf(e[k],   w4.x, acc); acc = fmaf(e[k+1], w4.y, acc);
    acc = fmaf(e[k+2], w4.z, acc); acc = fmaf(e[k+3], w4.w, acc);
  }
  embW[v*GG + g] = acc;
}

// ---------------- K2: LSTM, ONE WAVE per batch row ----------------
// Lane l owns hidden element l: computes all 4 gate dots (weights in ~256 VGPRs),
// c/h update fully lane-local. No barriers, no shuffles. h broadcast = 1 ds_write
// + 16 broadcast ds_read_b128, ordered by the wave's own in-order lgkmcnt.
__global__ __launch_bounds__(64) void k_lstm(const int* __restrict__ x,
                                             const float* __restrict__ embW,
                                             const float* __restrict__ w_hh,
                                             float* __restrict__ hout){
  int b = blockIdx.x, l = threadIdx.x;
  __shared__ __align__(16) float hsh[HH];
  // per-lane weights: rows l (i), 64+l (f), 128+l (g), 192+l (o) of w_hh
  float4 wi[16], wf[16], wg[16], wo4[16];
  {
    const float* ri = w_hh + (l      )*HH;
    const float* rf = w_hh + (l +  64)*HH;
    const float* rg = w_hh + (l + 128)*HH;
    const float* ro = w_hh + (l + 192)*HH;
#pragma unroll
    for (int k = 0; k < 16; k++){
      wi[k]  = *(const float4*)(ri + 4*k);
      wf[k]  = *(const float4*)(rf + 4*k);
      wg[k]  = *(const float4*)(rg + 4*k);
      wo4[k] = *(const float4*)(ro + 4*k);
    }
  }
  hsh[l] = 0.f;
  float c = 0.f;
  const int* xb = x + b*TT;
  int i0 = xb[0];
  // gates(x) for t=0
  float gi = embW[i0*GG +       l];
  float gf = embW[i0*GG +  64 + l];
  float gg = embW[i0*GG + 128 + l];
  float go = embW[i0*GG + 192 + l];
  int i1 = xb[1];
  float* houtb = hout + (size_t)b*TT*HH;
  const float4* hp = (const float4*)hsh;
  for (int t = 0; t < TT; t++){
    // prefetch gates(x) for t+1 (consumed next iteration; full step to land)
    float gi_n = embW[i1*GG +       l];
    float gf_n = embW[i1*GG +  64 + l];
    float gg_n = embW[i1*GG + 128 + l];
    float go_n = embW[i1*GG + 192 + l];
    int inx = xb[(t + 2 < TT) ? (t + 2) : (TT - 1)];
    // 4 independent fma chains (one per gate) over broadcast LDS reads of h
    float ai = gi, af = gf, ag = gg, ao = go;
#pragma unroll
    for (int k = 0; k < 16; k++){
      float4 hv = hp[k];                       // broadcast ds_read_b128 (uniform addr)
      ai = fmaf(wi[k].x,  hv.x, ai); ai = fmaf(wi[k].y,  hv.y, ai);
      ai = fmaf(wi[k].z,  hv.z, ai); ai = fmaf(wi[k].w,  hv.w, ai);
      af = fmaf(wf[k].x,  hv.x, af); af = fmaf(wf[k].y,  hv.y, af);
      af = fmaf(wf[k].z,  hv.z, af); af = fmaf(wf[k].w,  hv.w, af);
      ag = fmaf(wg[k].x,  hv.x, ag); ag = fmaf(wg[k].y,  hv.y, ag);
      ag = fmaf(wg[k].z,  hv.z, ag); ag = fmaf(wg[k].w,  hv.w, ag);
      ao = fmaf(wo4[k].x, hv.x, ao); ao = fmaf(wo4[k].y, hv.y, ao);
      ao = fmaf(wo4[k].z, hv.z, ao); ao = fmaf(wo4[k].w, hv.w, ao);
    }
    // nonlinearities (all lane-local; 4-way ILP on the gate nonlins)
    float vi = 1.f/(1.f + __expf(-ai));
    float vf = 1.f/(1.f + __expf(-af));
    float vg = 1.f - 2.f/(__expf(2.f*ag) + 1.f);   // tanh
    float vo = 1.f/(1.f + __expf(-ao));
    c = fmaf(vf, c, vi*vg);
    float th = 1.f - 2.f/(__expf(2.f*c) + 1.f);    // tanh(c)
    float h  = vo*th;
    hsh[l] = h;                                    // next iter's reads wait on lgkmcnt
    houtb[(size_t)t*HH + l] = h;                   // fire-and-forget global store
    gi = gi_n; gf = gf_n; gg = gg_n; go = go_n; i1 = inx;
  }
}

// ---------------- K3: fused MHA level, one workgroup per time step t ----------------
// attention is over the batch axis (64x64 per (t, head)); all staging in LDS (64KB)
__global__ __launch_bounds__(256) void k_mha(const float* __restrict__ hin,
                                             const float* __restrict__ wqkv,
                                             const float* __restrict__ bqkv,
                                             const float* __restrict__ wo,
                                             const float* __restrict__ bo,
                                             float* __restrict__ hout){
  int t = blockIdx.x, tid = threadIdx.x;
  __shared__ float xta[BB][HH];    // x column, later reused for attention output (16KB)
  __shared__ float qkvs[BB][192];  // qkv rows (48KB)

  // stage-2 weights (threads 0..191 own one output feature row)
  float wq[HH]; float bq = 0.f;
  if (tid < 192){
#pragma unroll
    for (int k = 0; k < HH; k += 4)
      *(float4*)&wq[k] = *(const float4*)(wqkv + tid*HH + k);
    bq = bqkv[tid];
  }
  // stage 1: load x[:, t, :] (64 rows x 64 fp32); thread loads 16 floats
  {
    int r = tid >> 2, q = tid & 3;
    const float* p = hin + (size_t)(r*TT + t)*HH + q*16;
#pragma unroll
    for (int j = 0; j < 16; j += 4)
      *(float4*)&xta[r][q*16 + j] = *(const float4*)(p + j);
  }
  bar_lds();
  // stage 2: qkv = x @ wqkv^T + bqkv
  if (tid < 192){
#pragma unroll 4
    for (int b = 0; b < BB; b++){
      float acc = bq;
#pragma unroll
      for (int k = 0; k < HH; k += 4){
        float4 xv = *(const float4*)&xta[b][k];        // broadcast
        acc = fmaf(wq[k],   xv.x, acc); acc = fmaf(wq[k+1], xv.y, acc);
        acc = fmaf(wq[k+2], xv.z, acc); acc = fmaf(wq[k+3], xv.w, acc);
      }
      qkvs[b][tid] = acc;
    }
  }
  bar_lds();
  // stage 3: attention; thread (head hd = wave, row l = lane)
  {
    int hd = tid >> 6, l = tid & 63;
    int qo = hd*16, ko = 64 + hd*16, vo = 128 + hd*16;
    float4 q0 = *(const float4*)&qkvs[l][qo];
    float4 q1 = *(const float4*)&qkvs[l][qo+4];
    float4 q2 = *(const float4*)&qkvs[l][qo+8];
    float4 q3 = *(const float4*)&qkvs[l][qo+12];
    float S[BB];
#pragma unroll
    for (int m = 0; m < BB; m++){
      float4 k0 = *(const float4*)&qkvs[m][ko];
      float4 k1 = *(const float4*)&qkvs[m][ko+4];
      float4 k2 = *(const float4*)&qkvs[m][ko+8];
      float4 k3 = *(const float4*)&qkvs[m][ko+12];
      float d;
      d = q0.x*k0.x;         d = fmaf(q0.y,k0.y,d); d = fmaf(q0.z,k0.z,d); d = fmaf(q0.w,k0.w,d);
      d = fmaf(q1.x,k1.x,d); d = fmaf(q1.y,k1.y,d); d = fmaf(q1.z,k1.z,d); d = fmaf(q1.w,k1.w,d);
      d = fmaf(q2.x,k2.x,d); d = fmaf(q2.y,k2.y,d); d = fmaf(q2.z,k2.z,d); d = fmaf(q2.w,k2.w,d);
      d = fmaf(q3.x,k3.x,d); d = fmaf(q3.y,k3.y,d); d = fmaf(q3.z,k3.z,d); d = fmaf(q3.w,k3.w,d);
      S[m] = 0.25f*d;
    }
    float mx = S[0];
#pragma unroll
    for (int m = 1; m < BB; m++) mx = fmaxf(mx, S[m]);
    float sum = 0.f;
#pragma unroll
    for (int m = 0; m < BB; m++){ S[m] = __expf(S[m] - mx); sum += S[m]; }
    float inv = 1.f/sum;
    float4 a0 = make_float4(0,0,0,0), a1 = a0, a2 = a0, a3 = a0;
#pragma unroll
    for (int m = 0; m < BB; m++){
      float s = S[m];
      float4 v0 = *(const float4*)&qkvs[m][vo];
      float4 v1 = *(const float4*)&qkvs[m][vo+4];
      float4 v2 = *(const float4*)&qkvs[m][vo+8];
      float4 v3 = *(const float4*)&qkvs[m][vo+12];
      a0.x = fmaf(s,v0.x,a0.x); a0.y = fmaf(s,v0.y,a0.y); a0.z = fmaf(s,v0.z,a0.z); a0.w = fmaf(s,v0.w,a0.w);
      a1.x = fmaf(s,v1.x,a1.x); a1.y = fmaf(s,v1.y,a1.y); a1.z = fmaf(s,v1.z,a1.z); a1.w = fmaf(s,v1.w,a1.w);
      a2.x = fmaf(s,v2.x,a2.x); a2.y = fmaf(s,v2.y,a2.y); a2.z = fmaf(s,v2.z,a2.z); a2.w = fmaf(s,v2.w,a2.w);
      a3.x = fmaf(s,v3.x,a3.x); a3.y = fmaf(s,v3.y,a3.y); a3.z = fmaf(s,v3.z,a3.z); a3.w = fmaf(s,v3.w,a3.w);
    }
    a0.x*=inv; a0.y*=inv; a0.z*=inv; a0.w*=inv;
    a1.x*=inv; a1.y*=inv; a1.z*=inv; a1.w*=inv;
    a2.x*=inv; a2.y*=inv; a2.z*=inv; a2.w*=inv;
    a3.x*=inv; a3.y*=inv; a3.z*=inv; a3.w*=inv;
    bar_lds();   // stage-2 readers of xta done before overwrite
    *(float4*)&xta[l][qo]    = a0;
    *(float4*)&xta[l][qo+4]  = a1;
    *(float4*)&xta[l][qo+8]  = a2;
    *(float4*)&xta[l][qo+12] = a3;
  }
  bar_lds();
  // stage 4: out projection; thread owns col c for 16 rows
  {
    int c = tid & 63, wg = tid >> 6;
    float wor[HH];
#pragma unroll
    for (int k = 0; k < HH; k += 4)
      *(float4*)&wor[k] = *(const float4*)(wo + c*HH + k);
    float bo4 = bo[c];
#pragma unroll 2
    for (int j = 0; j < 16; j++){
      int b = wg*16 + j;
      float acc = bo4;
#pragma unroll
      for (int k = 0; k < HH; k += 4){
        float4 xv = *(const float4*)&xta[b][k];        // broadcast
        acc = fmaf(wor[k],   xv.x, acc); acc = fmaf(wor[k+1], xv.y, acc);
        acc = fmaf(wor[k+2], xv.z, acc); acc = fmaf(wor[k+3], xv.w, acc);
      }
      hout[(size_t)(b*TT + t)*HH + c] = acc;
    }
  }
}

// ---------------- K4: LayerNorm + FC (ln folded into fc_w registers) ----------------
__global__ __launch_bounds__(256) void k_fc(const float* __restrict__ hin,
                                            const float* __restrict__ ln_g,
                                            const float* __restrict__ ln_b,
                                            const float* __restrict__ fc_w,
                                            const float* __restrict__ fc_b,
                                            float* __restrict__ out){
  int tid = threadIdx.x;
  __shared__ float tile[64][68];
  __shared__ float ps[64][4];
  __shared__ float pq[64][4];
  __shared__ float mu[64], rs[64];
  float w[HH];
  float wsum = 0.f, bias2 = fc_b[tid];
#pragma unroll
  for (int k = 0; k < HH; k += 4){
    float4 wv = *(const float4*)(fc_w + tid*HH + k);
    float4 gv = *(const float4*)(ln_g + k);
    float4 bv = *(const float4*)(ln_b + k);
    bias2 = fmaf(bv.x, wv.x, bias2); bias2 = fmaf(bv.y, wv.y, bias2);
    bias2 = fmaf(bv.z, wv.z, bias2); bias2 = fmaf(bv.w, wv.w, bias2);
    w[k]   = gv.x*wv.x; w[k+1] = gv.y*wv.y;
    w[k+2] = gv.z*wv.z; w[k+3] = gv.w*wv.w;
    wsum += w[k] + w[k+1] + w[k+2] + w[k+3];
  }
  int r = tid >> 2, q = tid & 3;
  for (int ti = 0; ti < 4; ti++){
    int rowbase = blockIdx.x*256 + ti*64;
    const float* p = hin + (size_t)(rowbase + r)*HH + q*16;
    float xv[16];
#pragma unroll
    for (int j = 0; j < 16; j += 4)
      *(float4*)&xv[j] = *(const float4*)(p + j);
    float s1 = 0.f, s2 = 0.f;
#pragma unroll
    for (int j = 0; j < 16; j++){ s1 += xv[j]; s2 = fmaf(xv[j], xv[j], s2); }
#pragma unroll
    for (int j = 0; j < 16; j += 4)
      *(float4*)&tile[r][q*16 + j] = *(const float4*)&xv[j];
    ps[r][q] = s1; pq[r][q] = s2;
    bar_lds();
    if (tid < 64){
      float4 a  = *(const float4*)&ps[tid][0];
      float4 b4 = *(const float4*)&pq[tid][0];
      float m = (a.x + a.y + a.z + a.w) * (1.f/64.f);
      float v = (b4.x + b4.y + b4.z + b4.w) * (1.f/64.f) - m*m;
      mu[tid] = m;
      rs[tid] = rsqrtf(v + 1e-5f);
    }
    bar_lds();
#pragma unroll 2
    for (int rr = 0; rr < 64; rr++){
      float acc = 0.f;
#pragma unroll
      for (int k = 0; k < HH; k += 4){
        float4 x4 = *(const float4*)&tile[rr][k];      // broadcast
        acc = fmaf(w[k],   x4.x, acc); acc = fmaf(w[k+1], x4.y, acc);
        acc = fmaf(w[k+2], x4.z, acc); acc = fmaf(w[k+3], x4.w, acc);
      }
      float o = rs[rr]*(acc - mu[rr]*wsum) + bias2;
      out[(size_t)(rowbase + rr)*VV + tid] = o;
    }
    bar_lds();
  }
}

extern "C" void kernel_launch(void* const* d_in, const int* in_sizes, int n_in,
                              void* d_out, int out_size, void* d_ws, size_t ws_size,
                              hipStream_t stream){
  (void)in_sizes; (void)n_in; (void)out_size; (void)ws_size;
  const int*   x    = (const int*)d_in[0];
  const float* emb  = (const float*)d_in[1];
  const float* w_ih = (const float*)d_in[2];
  const float* w_hh = (const float*)d_in[3];
  const float* b_ih = (const float*)d_in[4];
  const float* b_hh = (const float*)d_in[5];
  const float* wqkv = (const float*)d_in[6];
  const float* bqkv = (const float*)d_in[7];
  const float* wo   = (const float*)d_in[8];
  const float* bo   = (const float*)d_in[9];
  const float* ln_g = (const float*)d_in[10];
  const float* ln_b = (const float*)d_in[11];
  const float* fc_w = (const float*)d_in[12];
  const float* fc_b = (const float*)d_in[13];

  char* ws = (char*)d_ws;
  float* embW = (float*)ws;                               // 256*256*4 = 256KB
  float* bufA = (float*)(ws + (1<<20));                   // 32MB fp32 (B,T,H)
  float* bufB = bufA + (size_t)BB*TT*HH;                  // 32MB fp32

  k_embw<<<VV,  256, 0, stream>>>(emb, w_ih, b_ih, b_hh, embW);
  k_lstm<<<BB,   64, 0, stream>>>(x, embW, w_hh, bufA);
  k_mha <<<TT,  256, 0, stream>>>(bufA, wqkv,          bqkv,       wo,          bo,      bufB);
  k_mha <<<TT,  256, 0, stream>>>(bufB, wqkv + 192*64, bqkv + 192, wo + 64*64,  bo + 64, bufA);
  k_fc  <<<512, 256, 0, stream>>>(bufA, ln_g, ln_b, fc_w, fc_b, (float*)d_out);
}

// Round 3
// 1664.358 us; speedup vs baseline: 1.8495x; 1.8495x over previous
//
#include <hip/hip_runtime.h>

enum { TT = 2048, HH = 64, BB = 64, GG = 256, VV = 256 };

// LDS-only barrier: does NOT drain vmcnt (global loads/stores stay in flight).
// Safe when the barrier only protects LDS traffic (CK's block_sync_lds pattern).
static __device__ __forceinline__ void bar_lds(){
  asm volatile("s_waitcnt lgkmcnt(0)\n\ts_barrier" ::: "memory");
}

// wave-uniform broadcast of lane k's value via v_readlane (VALU pipe, not LDS pipe)
static __device__ __forceinline__ float rdlane(float v, int l){
  return __int_as_float(__builtin_amdgcn_readlane(__float_as_int(v), l));
}

// ---------------- K1: embW[v][g] = emb[v]·w_ih[g] + b_ih[g] + b_hh[g] ----------------
__global__ __launch_bounds__(256) void k_embw(const float* __restrict__ emb,
                                              const float* __restrict__ w_ih,
                                              const float* __restrict__ b_ih,
                                              const float* __restrict__ b_hh,
                                              float* __restrict__ embW){
  int v = blockIdx.x, g = threadIdx.x;
  __shared__ float e[HH];
  if (g < HH) e[g] = emb[v*HH + g];
  bar_lds();
  float acc = b_ih[g] + b_hh[g];
  const float* wr = w_ih + g*HH;
#pragma unroll
  for (int k = 0; k < HH; k += 4){
    float4 w4 = *(const float4*)(wr + k);
    acc = fmaf(e[k],   w4.x, acc); acc = fmaf(e[k+1], w4.y, acc);
    acc = fmaf(e[k+2], w4.z, acc); acc = fmaf(e[k+3], w4.w, acc);
  }
  embW[v*GG + g] = acc;
}

// ---------------- K2: LSTM, one workgroup (4 waves) per batch row ----------------
// Wave q owns hidden elems [16q,16q+16); lane l: elem = 16q+(l&15), gate = l>>4.
// h broadcast: ONE per-lane ds_read_b32 per wave, then v_readlane -> SGPR operands
// for the 64 FMAs (keeps the shared LDS pipe nearly empty; work on 4 VALU pipes).
// Gate gather intra-wave via 3 shfl_xor; double-buffered h; ONE barrier per step.
__global__ __launch_bounds__(256) void k_lstm(const int* __restrict__ x,
                                              const float* __restrict__ embW,
                                              const float* __restrict__ w_hh,
                                              float* __restrict__ hout){
  int b = blockIdx.x, tid = threadIdx.x;
  int q = tid >> 6, l = tid & 63;
  int gate = l >> 4, e = q*16 + (l & 15);
  int row  = gate*64 + e;                       // row in the 4H=256 gate space (i,f,g,o)
  __shared__ __align__(16) float hbuf[2][HH];   // double-buffered h
  float w[HH];
  {
    const float* wr = w_hh + row*HH;
#pragma unroll
    for (int k = 0; k < HH; k += 4)
      *(float4*)&w[k] = *(const float4*)(wr + k);
  }
  if (tid < HH) hbuf[0][tid] = 0.f;
  float c = 0.f;                                // true cell state lives in grp-0 lanes
  const int* xb = x + b*TT;
  int i0 = xb[0];
  float gx = embW[i0*GG + row];                 // gates(x) for t=0 (own row only)
  int i1 = xb[1];
  const bool g2 = (gate == 2);                  // g-gate uses tanh (branch-free below)
  float* houtb = hout + (size_t)b*TT*HH;
  bar_lds();
  for (int t = 0; t < TT; t++){
    float hv = hbuf[t & 1][l];                  // per-lane h read (conflict-free b32)
    float gxn = embW[i1*GG + row];              // prefetch t+1 gate-x (L2)
    int inx = xb[(t + 2 < TT) ? (t + 2) : (TT - 1)];
    // 64-wide dot: weights in VGPRs, h[k] broadcast via readlane (SGPR operand)
    float a0 = gx, a1 = 0.f, a2 = 0.f, a3 = 0.f;
#pragma unroll
    for (int k = 0; k < 16; k++){
      a0 = fmaf(w[k],      rdlane(hv, k),      a0);
      a1 = fmaf(w[16 + k], rdlane(hv, 16 + k), a1);
      a2 = fmaf(w[32 + k], rdlane(hv, 32 + k), a2);
      a3 = fmaf(w[48 + k], rdlane(hv, 48 + k), a3);
    }
    float acc = (a0 + a1) + (a2 + a3);
    // shared-exp nonlinearity: tanh(x) = 2*sigmoid(2x)-1 (one transcendental, no branch)
    float arg = g2 ? (2.f*acc) : acc;
    float s   = 1.f/(1.f + __expf(-arg));
    float val = g2 ? fmaf(2.f, s, -1.f) : s;
    // gather i,f,g,o intra-wave (meaningful combination in grp-0 lanes)
    float vi = val;
    float vf = __shfl_xor(val, 16);
    float vg = __shfl_xor(val, 32);
    float vo = __shfl_xor(val, 48);
    c = fmaf(vf, c, vi*vg);                     // garbage-but-bounded in grps 1-3
    float th = 1.f - 2.f/(__expf(2.f*c) + 1.f); // tanh(c)
    float h  = vo*th;
    if (l < 16){                                // grp-0 lanes publish h for this wave's elems
      hbuf[(t + 1) & 1][e] = h;
      houtb[(size_t)t*HH + e] = h;              // fire-and-forget (no vmcnt drain)
    }
    bar_lds();
    gx = gxn; i1 = inx;
  }
}

// ---------------- K3: fused MHA level, one workgroup per time step t ----------------
// attention is over the batch axis (64x64 per (t, head)); all staging in LDS (64KB)
__global__ __launch_bounds__(256) void k_mha(const float* __restrict__ hin,
                                             const float* __restrict__ wqkv,
                                             const float* __restrict__ bqkv,
                                             const float* __restrict__ wo,
                                             const float* __restrict__ bo,
                                             float* __restrict__ hout){
  int t = blockIdx.x, tid = threadIdx.x;
  __shared__ float xta[BB][HH];    // x column, later reused for attention output (16KB)
  __shared__ float qkvs[BB][192];  // qkv rows (48KB)

  // stage-2 weights (threads 0..191 own one output feature row)
  float wq[HH]; float bq = 0.f;
  if (tid < 192){
#pragma unroll
    for (int k = 0; k < HH; k += 4)
      *(float4*)&wq[k] = *(const float4*)(wqkv + tid*HH + k);
    bq = bqkv[tid];
  }
  // stage 1: load x[:, t, :] (64 rows x 64 fp32); thread loads 16 floats
  {
    int r = tid >> 2, q = tid & 3;
    const float* p = hin + (size_t)(r*TT + t)*HH + q*16;
#pragma unroll
    for (int j = 0; j < 16; j += 4)
      *(float4*)&xta[r][q*16 + j] = *(const float4*)(p + j);
  }
  bar_lds();
  // stage 2: qkv = x @ wqkv^T + bqkv
  if (tid < 192){
#pragma unroll 4
    for (int b = 0; b < BB; b++){
      float acc = bq;
#pragma unroll
      for (int k = 0; k < HH; k += 4){
        float4 xv = *(const float4*)&xta[b][k];        // broadcast
        acc = fmaf(wq[k],   xv.x, acc); acc = fmaf(wq[k+1], xv.y, acc);
        acc = fmaf(wq[k+2], xv.z, acc); acc = fmaf(wq[k+3], xv.w, acc);
      }
      qkvs[b][tid] = acc;
    }
  }
  bar_lds();
  // stage 3: attention; thread (head hd = wave, row l = lane)
  {
    int hd = tid >> 6, l = tid & 63;
    int qo = hd*16, ko = 64 + hd*16, vo = 128 + hd*16;
    float4 q0 = *(const float4*)&qkvs[l][qo];
    float4 q1 = *(const float4*)&qkvs[l][qo+4];
    float4 q2 = *(const float4*)&qkvs[l][qo+8];
    float4 q3 = *(const float4*)&qkvs[l][qo+12];
    float S[BB];
#pragma unroll
    for (int m = 0; m < BB; m++){
      float4 k0 = *(const float4*)&qkvs[m][ko];
      float4 k1 = *(const float4*)&qkvs[m][ko+4];
      float4 k2 = *(const float4*)&qkvs[m][ko+8];
      float4 k3 = *(const float4*)&qkvs[m][ko+12];
      float d;
      d = q0.x*k0.x;         d = fmaf(q0.y,k0.y,d); d = fmaf(q0.z,k0.z,d); d = fmaf(q0.w,k0.w,d);
      d = fmaf(q1.x,k1.x,d); d = fmaf(q1.y,k1.y,d); d = fmaf(q1.z,k1.z,d); d = fmaf(q1.w,k1.w,d);
      d = fmaf(q2.x,k2.x,d); d = fmaf(q2.y,k2.y,d); d = fmaf(q2.z,k2.z,d); d = fmaf(q2.w,k2.w,d);
      d = fmaf(q3.x,k3.x,d); d = fmaf(q3.y,k3.y,d); d = fmaf(q3.z,k3.z,d); d = fmaf(q3.w,k3.w,d);
      S[m] = 0.25f*d;
    }
    float mx = S[0];
#pragma unroll
    for (int m = 1; m < BB; m++) mx = fmaxf(mx, S[m]);
    float sum = 0.f;
#pragma unroll
    for (int m = 0; m < BB; m++){ S[m] = __expf(S[m] - mx); sum += S[m]; }
    float inv = 1.f/sum;
    float4 a0 = make_float4(0,0,0,0), a1 = a0, a2 = a0, a3 = a0;
#pragma unroll
    for (int m = 0; m < BB; m++){
      float s = S[m];
      float4 v0 = *(const float4*)&qkvs[m][vo];
      float4 v1 = *(const float4*)&qkvs[m][vo+4];
      float4 v2 = *(const float4*)&qkvs[m][vo+8];
      float4 v3 = *(const float4*)&qkvs[m][vo+12];
      a0.x = fmaf(s,v0.x,a0.x); a0.y = fmaf(s,v0.y,a0.y); a0.z = fmaf(s,v0.z,a0.z); a0.w = fmaf(s,v0.w,a0.w);
      a1.x = fmaf(s,v1.x,a1.x); a1.y = fmaf(s,v1.y,a1.y); a1.z = fmaf(s,v1.z,a1.z); a1.w = fmaf(s,v1.w,a1.w);
      a2.x = fmaf(s,v2.x,a2.x); a2.y = fmaf(s,v2.y,a2.y); a2.z = fmaf(s,v2.z,a2.z); a2.w = fmaf(s,v2.w,a2.w);
      a3.x = fmaf(s,v3.x,a3.x); a3.y = fmaf(s,v3.y,a3.y); a3.z = fmaf(s,v3.z,a3.z); a3.w = fmaf(s,v3.w,a3.w);
    }
    a0.x*=inv; a0.y*=inv; a0.z*=inv; a0.w*=inv;
    a1.x*=inv; a1.y*=inv; a1.z*=inv; a1.w*=inv;
    a2.x*=inv; a2.y*=inv; a2.z*=inv; a2.w*=inv;
    a3.x*=inv; a3.y*=inv; a3.z*=inv; a3.w*=inv;
    bar_lds();   // stage-2 readers of xta done before overwrite
    *(float4*)&xta[l][qo]    = a0;
    *(float4*)&xta[l][qo+4]  = a1;
    *(float4*)&xta[l][qo+8]  = a2;
    *(float4*)&xta[l][qo+12] = a3;
  }
  bar_lds();
  // stage 4: out projection; thread owns col c for 16 rows
  {
    int c = tid & 63, wg = tid >> 6;
    float wor[HH];
#pragma unroll
    for (int k = 0; k < HH; k += 4)
      *(float4*)&wor[k] = *(const float4*)(wo + c*HH + k);
    float bo4 = bo[c];
#pragma unroll 2
    for (int j = 0; j < 16; j++){
      int b = wg*16 + j;
      float acc = bo4;
#pragma unroll
      for (int k = 0; k < HH; k += 4){
        float4 xv = *(const float4*)&xta[b][k];        // broadcast
        acc = fmaf(wor[k],   xv.x, acc); acc = fmaf(wor[k+1], xv.y, acc);
        acc = fmaf(wor[k+2], xv.z, acc); acc = fmaf(wor[k+3], xv.w, acc);
      }
      hout[(size_t)(b*TT + t)*HH + c] = acc;
    }
  }
}

// ---------------- K4: LayerNorm + FC (ln folded into fc_w registers) ----------------
__global__ __launch_bounds__(256) void k_fc(const float* __restrict__ hin,
                                            const float* __restrict__ ln_g,
                                            const float* __restrict__ ln_b,
                                            const float* __restrict__ fc_w,
                                            const float* __restrict__ fc_b,
                                            float* __restrict__ out){
  int tid = threadIdx.x;
  __shared__ float tile[64][68];
  __shared__ float ps[64][4];
  __shared__ float pq[64][4];
  __shared__ float mu[64], rs[64];
  float w[HH];
  float wsum = 0.f, bias2 = fc_b[tid];
#pragma unroll
  for (int k = 0; k < HH; k += 4){
    float4 wv = *(const float4*)(fc_w + tid*HH + k);
    float4 gv = *(const float4*)(ln_g + k);
    float4 bv = *(const float4*)(ln_b + k);
    bias2 = fmaf(bv.x, wv.x, bias2); bias2 = fmaf(bv.y, wv.y, bias2);
    bias2 = fmaf(bv.z, wv.z, bias2); bias2 = fmaf(bv.w, wv.w, bias2);
    w[k]   = gv.x*wv.x; w[k+1] = gv.y*wv.y;
    w[k+2] = gv.z*wv.z; w[k+3] = gv.w*wv.w;
    wsum += w[k] + w[k+1] + w[k+2] + w[k+3];
  }
  int r = tid >> 2, q = tid & 3;
  for (int ti = 0; ti < 4; ti++){
    int rowbase = blockIdx.x*256 + ti*64;
    const float* p = hin + (size_t)(rowbase + r)*HH + q*16;
    float xv[16];
#pragma unroll
    for (int j = 0; j < 16; j += 4)
      *(float4*)&xv[j] = *(const float4*)(p + j);
    float s1 = 0.f, s2 = 0.f;
#pragma unroll
    for (int j = 0; j < 16; j++){ s1 += xv[j]; s2 = fmaf(xv[j], xv[j], s2); }
#pragma unroll
    for (int j = 0; j < 16; j += 4)
      *(float4*)&tile[r][q*16 + j] = *(const float4*)&xv[j];
    ps[r][q] = s1; pq[r][q] = s2;
    bar_lds();
    if (tid < 64){
      float4 a  = *(const float4*)&ps[tid][0];
      float4 b4 = *(const float4*)&pq[tid][0];
      float m = (a.x + a.y + a.z + a.w) * (1.f/64.f);
      float v = (b4.x + b4.y + b4.z + b4.w) * (1.f/64.f) - m*m;
      mu[tid] = m;
      rs[tid] = rsqrtf(v + 1e-5f);
    }
    bar_lds();
#pragma unroll 2
    for (int rr = 0; rr < 64; rr++){
      float acc = 0.f;
#pragma unroll
      for (int k = 0; k < HH; k += 4){
        float4 x4 = *(const float4*)&tile[rr][k];      // broadcast
        acc = fmaf(w[k],   x4.x, acc); acc = fmaf(w[k+1], x4.y, acc);
        acc = fmaf(w[k+2], x4.z, acc); acc = fmaf(w[k+3], x4.w, acc);
      }
      float o = rs[rr]*(acc - mu[rr]*wsum) + bias2;
      out[(size_t)(rowbase + rr)*VV + tid] = o;
    }
    bar_lds();
  }
}

extern "C" void kernel_launch(void* const* d_in, const int* in_sizes, int n_in,
                              void* d_out, int out_size, void* d_ws, size_t ws_size,
                              hipStream_t stream){
  (void)in_sizes; (void)n_in; (void)out_size; (void)ws_size;
  const int*   x    = (const int*)d_in[0];
  const float* emb  = (const float*)d_in[1];
  const float* w_ih = (const float*)d_in[2];
  const float* w_hh = (const float*)d_in[3];
  const float* b_ih = (const float*)d_in[4];
  const float* b_hh = (const float*)d_in[5];
  const float* wqkv = (const float*)d_in[6];
  const float* bqkv = (const float*)d_in[7];
  const float* wo   = (const float*)d_in[8];
  const float* bo   = (const float*)d_in[9];
  const float* ln_g = (const float*)d_in[10];
  const float* ln_b = (const float*)d_in[11];
  const float* fc_w = (const float*)d_in[12];
  const float* fc_b = (const float*)d_in[13];

  char* ws = (char*)d_ws;
  float* embW = (float*)ws;                               // 256*256*4 = 256KB
  float* bufA = (float*)(ws + (1<<20));                   // 32MB fp32 (B,T,H)
  float* bufB = bufA + (size_t)BB*TT*HH;                  // 32MB fp32

  k_embw<<<VV,  256, 0, stream>>>(emb, w_ih, b_ih, b_hh, embW);
  k_lstm<<<BB,  256, 0, stream>>>(x, embW, w_hh, bufA);
  k_mha <<<TT,  256, 0, stream>>>(bufA, wqkv,          bqkv,       wo,          bo,      bufB);
  k_mha <<<TT,  256, 0, stream>>>(bufB, wqkv + 192*64, bqkv + 192, wo + 64*64,  bo + 64, bufA);
  k_fc  <<<512, 256, 0, stream>>>(bufA, ln_g, ln_b, fc_w, fc_b, (float*)d_out);
}

// Round 4
// 1663.174 us; speedup vs baseline: 1.8509x; 1.0007x over previous
//
#include <hip/hip_runtime.h>

enum { TT = 2048, HH = 64, BB = 64, GG = 256, VV = 256 };

// LDS-only barrier: does NOT drain vmcnt (global loads/stores stay in flight).
static __device__ __forceinline__ void bar_lds(){
  asm volatile("s_waitcnt lgkmcnt(0)\n\ts_barrier" ::: "memory");
}

// wave-uniform broadcast of lane k's value via v_readlane (VALU pipe, not LDS pipe)
#define RL(H,k) __int_as_float(__builtin_amdgcn_readlane(__float_as_int(H), (k)))
// acc += W(.x..w) * h[B..B+3] with W a named float4 register (no array indexing)
#define FMA4(acc, W, H, B) do{ \
  acc = fmaf((W).x, RL(H,(B)+0), acc); \
  acc = fmaf((W).y, RL(H,(B)+1), acc); \
  acc = fmaf((W).z, RL(H,(B)+2), acc); \
  acc = fmaf((W).w, RL(H,(B)+3), acc); }while(0)
// acc += dot(U, X) for two float4s
#define MAC4(acc, U, X) do{ \
  acc = fmaf((U).x, (X).x, acc); \
  acc = fmaf((U).y, (X).y, acc); \
  acc = fmaf((U).z, (X).z, acc); \
  acc = fmaf((U).w, (X).w, acc); }while(0)

// ---------------- K1: embW[v][g] = emb[v]·w_ih[g] + b_ih[g] + b_hh[g] ----------------
__global__ __launch_bounds__(256) void k_embw(const float* __restrict__ emb,
                                              const float* __restrict__ w_ih,
                                              const float* __restrict__ b_ih,
                                              const float* __restrict__ b_hh,
                                              float* __restrict__ embW){
  int v = blockIdx.x, g = threadIdx.x;
  __shared__ float e[HH];
  if (g < HH) e[g] = emb[v*HH + g];
  bar_lds();
  float acc = b_ih[g] + b_hh[g];
  const float* wr = w_ih + g*HH;
#pragma unroll
  for (int k = 0; k < HH; k += 4){
    float4 w4 = *(const float4*)(wr + k);
    acc = fmaf(e[k],   w4.x, acc); acc = fmaf(e[k+1], w4.y, acc);
    acc = fmaf(e[k+2], w4.z, acc); acc = fmaf(e[k+3], w4.w, acc);
  }
  embW[v*GG + g] = acc;
}

// ---------------- K2: LSTM, one workgroup (4 waves) per batch row ----------------
// Wave q owns hidden elems [16q,16q+16); lane l: elem = 16q+(l&15), gate = l>>4.
// h broadcast via v_readlane (SGPR operands); weights in 16 NAMED float4 registers
// (r3's float w[64] array was demoted — VGPR_Count=44 — causing per-step re-loads).
__global__ __launch_bounds__(256) void k_lstm(const int* __restrict__ x,
                                              const float* __restrict__ embW,
                                              const float* __restrict__ w_hh,
                                              float* __restrict__ hout){
  int b = blockIdx.x, tid = threadIdx.x;
  int q = tid >> 6, l = tid & 63;
  int gate = l >> 4, e = q*16 + (l & 15);
  int row  = gate*64 + e;                       // row in the 4H=256 gate space (i,f,g,o)
  __shared__ __align__(16) float hbuf[2][HH];   // double-buffered h
  const float4* W4 = (const float4*)(w_hh + row*HH);
  float4 w0  = W4[0],  w1  = W4[1],  w2  = W4[2],  w3  = W4[3];
  float4 w4_ = W4[4],  w5  = W4[5],  w6  = W4[6],  w7  = W4[7];
  float4 w8  = W4[8],  w9  = W4[9],  w10 = W4[10], w11 = W4[11];
  float4 w12 = W4[12], w13 = W4[13], w14 = W4[14], w15 = W4[15];
  if (tid < HH) hbuf[0][tid] = 0.f;
  float c = 0.f;                                // true cell state lives in grp-0 lanes
  const int* xb = x + b*TT;
  int i0 = xb[0];
  float gx = embW[i0*GG + row];                 // gates(x) for t=0 (own row only)
  int i1 = xb[1];
  const bool g2 = (gate == 2);                  // g-gate uses tanh (branch-free below)
  float* houtb = hout + (size_t)b*TT*HH;
  bar_lds();
  for (int t = 0; t < TT; t++){
    float hv = hbuf[t & 1][l];                  // per-lane h read (conflict-free b32)
    float gxn = embW[i1*GG + row];              // prefetch t+1 gate-x (L2)
    int inx = xb[(t + 2 < TT) ? (t + 2) : (TT - 1)];
    // 64-wide dot: weights in named VGPRs, h[k] broadcast via readlane (SGPR operand)
    float a0 = gx, a1 = 0.f, a2 = 0.f, a3 = 0.f;
    FMA4(a0, w0,  hv, 0);  FMA4(a0, w1,  hv, 4);  FMA4(a0, w2,  hv, 8);  FMA4(a0, w3,  hv, 12);
    FMA4(a1, w4_, hv, 16); FMA4(a1, w5,  hv, 20); FMA4(a1, w6,  hv, 24); FMA4(a1, w7,  hv, 28);
    FMA4(a2, w8,  hv, 32); FMA4(a2, w9,  hv, 36); FMA4(a2, w10, hv, 40); FMA4(a2, w11, hv, 44);
    FMA4(a3, w12, hv, 48); FMA4(a3, w13, hv, 52); FMA4(a3, w14, hv, 56); FMA4(a3, w15, hv, 60);
    float acc = (a0 + a1) + (a2 + a3);
    // shared-exp nonlinearity: tanh(x) = 2*sigmoid(2x)-1 (one transcendental, no branch)
    float arg = g2 ? (2.f*acc) : acc;
    float s   = 1.f/(1.f + __expf(-arg));
    float val = g2 ? fmaf(2.f, s, -1.f) : s;
    // gather i,f,g,o intra-wave (meaningful combination in grp-0 lanes)
    float vi = val;
    float vf = __shfl_xor(val, 16);
    float vg = __shfl_xor(val, 32);
    float vo = __shfl_xor(val, 48);
    c = fmaf(vf, c, vi*vg);                     // garbage-but-bounded in grps 1-3
    float th = 1.f - 2.f/(__expf(2.f*c) + 1.f); // tanh(c)
    float h  = vo*th;
    if (l < 16){                                // grp-0 lanes publish h for this wave's elems
      hbuf[(t + 1) & 1][e] = h;
      houtb[(size_t)t*HH + e] = h;              // fire-and-forget (no vmcnt drain)
    }
    bar_lds();
    gx = gxn; i1 = inx;
  }
}

// ---------------- K3: fused MHA level, one workgroup per time step t ----------------
// attention is over the batch axis (64x64 per (t, head)); all staging in LDS (64KB)
__global__ __launch_bounds__(256) void k_mha(const float* __restrict__ hin,
                                             const float* __restrict__ wqkv,
                                             const float* __restrict__ bqkv,
                                             const float* __restrict__ wo,
                                             const float* __restrict__ bo,
                                             float* __restrict__ hout){
  int t = blockIdx.x, tid = threadIdx.x;
  __shared__ float xta[BB][HH];    // x column, later reused for attention output (16KB)
  __shared__ float qkvs[BB][192];  // qkv rows (48KB)

  // stage-2 weights in NAMED float4 registers (threads 0..191 own one output row)
  int tw = (tid < 192) ? tid : 0;
  const float4* wp = (const float4*)(wqkv + tw*HH);
  float4 u0  = wp[0],  u1  = wp[1],  u2  = wp[2],  u3  = wp[3];
  float4 u4  = wp[4],  u5  = wp[5],  u6  = wp[6],  u7  = wp[7];
  float4 u8  = wp[8],  u9  = wp[9],  u10 = wp[10], u11 = wp[11];
  float4 u12 = wp[12], u13 = wp[13], u14 = wp[14], u15 = wp[15];
  float bq = bqkv[tw];
  // stage 1: load x[:, t, :] (64 rows x 64 fp32); thread loads 16 floats
  {
    int r = tid >> 2, q = tid & 3;
    const float* p = hin + (size_t)(r*TT + t)*HH + q*16;
#pragma unroll
    for (int j = 0; j < 16; j += 4)
      *(float4*)&xta[r][q*16 + j] = *(const float4*)(p + j);
  }
  bar_lds();
  // stage 2: qkv = x @ wqkv^T + bqkv
  if (tid < 192){
#pragma unroll 4
    for (int b = 0; b < BB; b++){
      const float4* xp = (const float4*)&xta[b][0];    // broadcast b128 reads
      float acc = bq;
      float4 xv;
      xv = xp[0];  MAC4(acc, u0,  xv);
      xv = xp[1];  MAC4(acc, u1,  xv);
      xv = xp[2];  MAC4(acc, u2,  xv);
      xv = xp[3];  MAC4(acc, u3,  xv);
      xv = xp[4];  MAC4(acc, u4,  xv);
      xv = xp[5];  MAC4(acc, u5,  xv);
      xv = xp[6];  MAC4(acc, u6,  xv);
      xv = xp[7];  MAC4(acc, u7,  xv);
      xv = xp[8];  MAC4(acc, u8,  xv);
      xv = xp[9];  MAC4(acc, u9,  xv);
      xv = xp[10]; MAC4(acc, u10, xv);
      xv = xp[11]; MAC4(acc, u11, xv);
      xv = xp[12]; MAC4(acc, u12, xv);
      xv = xp[13]; MAC4(acc, u13, xv);
      xv = xp[14]; MAC4(acc, u14, xv);
      xv = xp[15]; MAC4(acc, u15, xv);
      qkvs[b][tid] = acc;
    }
  }
  bar_lds();
  // stage 3: attention; thread (head hd = wave, row l = lane)
  {
    int hd = tid >> 6, l = tid & 63;
    int qo = hd*16, ko = 64 + hd*16, vo = 128 + hd*16;
    float4 q0 = *(const float4*)&qkvs[l][qo];
    float4 q1 = *(const float4*)&qkvs[l][qo+4];
    float4 q2 = *(const float4*)&qkvs[l][qo+8];
    float4 q3 = *(const float4*)&qkvs[l][qo+12];
    float S[BB];
#pragma unroll
    for (int m = 0; m < BB; m++){
      float4 k0 = *(const float4*)&qkvs[m][ko];
      float4 k1 = *(const float4*)&qkvs[m][ko+4];
      float4 k2 = *(const float4*)&qkvs[m][ko+8];
      float4 k3 = *(const float4*)&qkvs[m][ko+12];
      float d;
      d = q0.x*k0.x;         d = fmaf(q0.y,k0.y,d); d = fmaf(q0.z,k0.z,d); d = fmaf(q0.w,k0.w,d);
      d = fmaf(q1.x,k1.x,d); d = fmaf(q1.y,k1.y,d); d = fmaf(q1.z,k1.z,d); d = fmaf(q1.w,k1.w,d);
      d = fmaf(q2.x,k2.x,d); d = fmaf(q2.y,k2.y,d); d = fmaf(q2.z,k2.z,d); d = fmaf(q2.w,k2.w,d);
      d = fmaf(q3.x,k3.x,d); d = fmaf(q3.y,k3.y,d); d = fmaf(q3.z,k3.z,d); d = fmaf(q3.w,k3.w,d);
      S[m] = 0.25f*d;
    }
    float mx = S[0];
#pragma unroll
    for (int m = 1; m < BB; m++) mx = fmaxf(mx, S[m]);
    float sum = 0.f;
#pragma unroll
    for (int m = 0; m < BB; m++){ S[m] = __expf(S[m] - mx); sum += S[m]; }
    float inv = 1.f/sum;
    float4 a0 = make_float4(0,0,0,0), a1 = a0, a2 = a0, a3 = a0;
#pragma unroll
    for (int m = 0; m < BB; m++){
      float s = S[m];
      float4 v0 = *(const float4*)&qkvs[m][vo];
      float4 v1 = *(const float4*)&qkvs[m][vo+4];
      float4 v2 = *(const float4*)&qkvs[m][vo+8];
      float4 v3 = *(const float4*)&qkvs[m][vo+12];
      a0.x = fmaf(s,v0.x,a0.x); a0.y = fmaf(s,v0.y,a0.y); a0.z = fmaf(s,v0.z,a0.z); a0.w = fmaf(s,v0.w,a0.w);
      a1.x = fmaf(s,v1.x,a1.x); a1.y = fmaf(s,v1.y,a1.y); a1.z = fmaf(s,v1.z,a1.z); a1.w = fmaf(s,v1.w,a1.w);
      a2.x = fmaf(s,v2.x,a2.x); a2.y = fmaf(s,v2.y,a2.y); a2.z = fmaf(s,v2.z,a2.z); a2.w = fmaf(s,v2.w,a2.w);
      a3.x = fmaf(s,v3.x,a3.x); a3.y = fmaf(s,v3.y,a3.y); a3.z = fmaf(s,v3.z,a3.z); a3.w = fmaf(s,v3.w,a3.w);
    }
    a0.x*=inv; a0.y*=inv; a0.z*=inv; a0.w*=inv;
    a1.x*=inv; a1.y*=inv; a1.z*=inv; a1.w*=inv;
    a2.x*=inv; a2.y*=inv; a2.z*=inv; a2.w*=inv;
    a3.x*=inv; a3.y*=inv; a3.z*=inv; a3.w*=inv;
    bar_lds();   // stage-2 readers of xta done before overwrite
    *(float4*)&xta[l][qo]    = a0;
    *(float4*)&xta[l][qo+4]  = a1;
    *(float4*)&xta[l][qo+8]  = a2;
    *(float4*)&xta[l][qo+12] = a3;
  }
  bar_lds();
  // stage 4: out projection; thread owns col c for 16 rows (weights in named regs)
  {
    int c = tid & 63, wg = tid >> 6;
    const float4* wop = (const float4*)(wo + c*HH);
    float4 o0  = wop[0],  o1  = wop[1],  o2  = wop[2],  o3  = wop[3];
    float4 o4  = wop[4],  o5  = wop[5],  o6  = wop[6],  o7  = wop[7];
    float4 o8  = wop[8],  o9  = wop[9],  o10 = wop[10], o11 = wop[11];
    float4 o12 = wop[12], o13 = wop[13], o14 = wop[14], o15 = wop[15];
    float bo4 = bo[c];
#pragma unroll 2
    for (int j = 0; j < 16; j++){
      int b = wg*16 + j;
      const float4* xp = (const float4*)&xta[b][0];    // broadcast b128 reads
      float acc = bo4;
      float4 xv;
      xv = xp[0];  MAC4(acc, o0,  xv);
      xv = xp[1];  MAC4(acc, o1,  xv);
      xv = xp[2];  MAC4(acc, o2,  xv);
      xv = xp[3];  MAC4(acc, o3,  xv);
      xv = xp[4];  MAC4(acc, o4,  xv);
      xv = xp[5];  MAC4(acc, o5,  xv);
      xv = xp[6];  MAC4(acc, o6,  xv);
      xv = xp[7];  MAC4(acc, o7,  xv);
      xv = xp[8];  MAC4(acc, o8,  xv);
      xv = xp[9];  MAC4(acc, o9,  xv);
      xv = xp[10]; MAC4(acc, o10, xv);
      xv = xp[11]; MAC4(acc, o11, xv);
      xv = xp[12]; MAC4(acc, o12, xv);
      xv = xp[13]; MAC4(acc, o13, xv);
      xv = xp[14]; MAC4(acc, o14, xv);
      xv = xp[15]; MAC4(acc, o15, xv);
      hout[(size_t)(b*TT + t)*HH + c] = acc;
    }
  }
}

// ---------------- K4: LayerNorm + FC (ln folded into fc_w, weights in named regs) ----------------
__global__ __launch_bounds__(256) void k_fc(const float* __restrict__ hin,
                                            const float* __restrict__ ln_g,
                                            const float* __restrict__ ln_b,
                                            const float* __restrict__ fc_w,
                                            const float* __restrict__ fc_b,
                                            float* __restrict__ out){
  int tid = threadIdx.x;
  __shared__ float tile[64][68];
  __shared__ float ps[64][4];
  __shared__ float pq[64][4];
  __shared__ float mu[64], rs[64];
  const float4* fwp = (const float4*)(fc_w + tid*HH);
  const float4* gvp = (const float4*)ln_g;
  const float4* bvp = (const float4*)ln_b;
  float wsum = 0.f, bias2 = fc_b[tid];
  float4 w0, w1, w2, w3, w4_, w5, w6, w7, w8, w9, w10, w11, w12, w13, w14, w15;
#define LNW(Wn, i) do{ \
    float4 fw = fwp[i]; float4 gv = gvp[i]; float4 bv = bvp[i]; \
    bias2 = fmaf(bv.x, fw.x, bias2); bias2 = fmaf(bv.y, fw.y, bias2); \
    bias2 = fmaf(bv.z, fw.z, bias2); bias2 = fmaf(bv.w, fw.w, bias2); \
    Wn = make_float4(gv.x*fw.x, gv.y*fw.y, gv.z*fw.z, gv.w*fw.w); \
    wsum += Wn.x + Wn.y + Wn.z + Wn.w; }while(0)
  LNW(w0,0);  LNW(w1,1);  LNW(w2,2);  LNW(w3,3);
  LNW(w4_,4); LNW(w5,5);  LNW(w6,6);  LNW(w7,7);
  LNW(w8,8);  LNW(w9,9);  LNW(w10,10); LNW(w11,11);
  LNW(w12,12); LNW(w13,13); LNW(w14,14); LNW(w15,15);
#undef LNW
  int r = tid >> 2, q = tid & 3;
  for (int ti = 0; ti < 4; ti++){
    int rowbase = blockIdx.x*256 + ti*64;
    const float* p = hin + (size_t)(rowbase + r)*HH + q*16;
    float xv[16];
#pragma unroll
    for (int j = 0; j < 16; j += 4)
      *(float4*)&xv[j] = *(const float4*)(p + j);
    float s1 = 0.f, s2 = 0.f;
#pragma unroll
    for (int j = 0; j < 16; j++){ s1 += xv[j]; s2 = fmaf(xv[j], xv[j], s2); }
#pragma unroll
    for (int j = 0; j < 16; j += 4)
      *(float4*)&tile[r][q*16 + j] = *(const float4*)&xv[j];
    ps[r][q] = s1; pq[r][q] = s2;
    bar_lds();
    if (tid < 64){
      float4 a  = *(const float4*)&ps[tid][0];
      float4 b4 = *(const float4*)&pq[tid][0];
      float m = (a.x + a.y + a.z + a.w) * (1.f/64.f);
      float v = (b4.x + b4.y + b4.z + b4.w) * (1.f/64.f) - m*m;
      mu[tid] = m;
      rs[tid] = rsqrtf(v + 1e-5f);
    }
    bar_lds();
#pragma unroll 2
    for (int rr = 0; rr < 64; rr++){
      const float4* tp = (const float4*)&tile[rr][0];  // broadcast b128 reads
      float acc = 0.f;
      float4 x4;
      x4 = tp[0];  MAC4(acc, w0,  x4);
      x4 = tp[1];  MAC4(acc, w1,  x4);
      x4 = tp[2];  MAC4(acc, w2,  x4);
      x4 = tp[3];  MAC4(acc, w3,  x4);
      x4 = tp[4];  MAC4(acc, w4_, x4);
      x4 = tp[5];  MAC4(acc, w5,  x4);
      x4 = tp[6];  MAC4(acc, w6,  x4);
      x4 = tp[7];  MAC4(acc, w7,  x4);
      x4 = tp[8];  MAC4(acc, w8,  x4);
      x4 = tp[9];  MAC4(acc, w9,  x4);
      x4 = tp[10]; MAC4(acc, w10, x4);
      x4 = tp[11]; MAC4(acc, w11, x4);
      x4 = tp[12]; MAC4(acc, w12, x4);
      x4 = tp[13]; MAC4(acc, w13, x4);
      x4 = tp[14]; MAC4(acc, w14, x4);
      x4 = tp[15]; MAC4(acc, w15, x4);
      float o = rs[rr]*(acc - mu[rr]*wsum) + bias2;
      out[(size_t)(rowbase + rr)*VV + tid] = o;
    }
    bar_lds();
  }
}

extern "C" void kernel_launch(void* const* d_in, const int* in_sizes, int n_in,
                              void* d_out, int out_size, void* d_ws, size_t ws_size,
                              hipStream_t stream){
  (void)in_sizes; (void)n_in; (void)out_size; (void)ws_size;
  const int*   x    = (const int*)d_in[0];
  const float* emb  = (const float*)d_in[1];
  const float* w_ih = (const float*)d_in[2];
  const float* w_hh = (const float*)d_in[3];
  const float* b_ih = (const float*)d_in[4];
  const float* b_hh = (const float*)d_in[5];
  const float* wqkv = (const float*)d_in[6];
  const float* bqkv = (const float*)d_in[7];
  const float* wo   = (const float*)d_in[8];
  const float* bo   = (const float*)d_in[9];
  const float* ln_g = (const float*)d_in[10];
  const float* ln_b = (const float*)d_in[11];
  const float* fc_w = (const float*)d_in[12];
  const float* fc_b = (const float*)d_in[13];

  char* ws = (char*)d_ws;
  float* embW = (float*)ws;                               // 256*256*4 = 256KB
  float* bufA = (float*)(ws + (1<<20));                   // 32MB fp32 (B,T,H)
  float* bufB = bufA + (size_t)BB*TT*HH;                  // 32MB fp32

  k_embw<<<VV,  256, 0, stream>>>(emb, w_ih, b_ih, b_hh, embW);
  k_lstm<<<BB,  256, 0, stream>>>(x, embW, w_hh, bufA);
  k_mha <<<TT,  256, 0, stream>>>(bufA, wqkv,          bqkv,       wo,          bo,      bufB);
  k_mha <<<TT,  256, 0, stream>>>(bufB, wqkv + 192*64, bqkv + 192, wo + 64*64,  bo + 64, bufA);
  k_fc  <<<512, 256, 0, stream>>>(bufA, ln_g, ln_b, fc_w, fc_b, (float*)d_out);
}